// Round 4
// baseline (682.549 us; speedup 1.0000x reference)
//
#include <hip/hip_runtime.h>
#include <hip/hip_bf16.h>
#include <cstdint>

// Problem constants: B=8, L=4096, D=768, Y=2048
#define BB 8
#define LL 4096
#define DD 768
#define YY 2048

typedef unsigned short u16;
typedef __bf16 bf16x8 __attribute__((ext_vector_type(8)));
typedef float f32x4 __attribute__((ext_vector_type(4)));

__device__ __forceinline__ u16 f2bf(float f) {
    uint32_t u = __float_as_uint(f);
    u += 0x7fffu + ((u >> 16) & 1u);   // RNE
    return (u16)(u >> 16);
}

// ---------------- cast U (Y*D = 1,572,864 floats) ----------------
__global__ __launch_bounds__(256) void cast_u_k(const float* __restrict__ U, u16* __restrict__ U16) {
    int i = blockIdx.x * 256 + threadIdx.x;          // one float4 per thread
    float4 v = ((const float4*)U)[i];
    ushort4 h;
    h.x = f2bf(v.x); h.y = f2bf(v.y); h.z = f2bf(v.z); h.w = f2bf(v.w);
    ((ushort4*)U16)[i] = h;
}

// -------- cast x -> x16 (B,L,D) bf16 AND xt (B,D,L) bf16 (transpose) --------
__global__ __launch_bounds__(256) void cast_transpose_x_k(const float* __restrict__ x,
                                                          u16* __restrict__ x16,
                                                          u16* __restrict__ xt) {
    __shared__ u16 tile[64 * 65];
    const int d0 = blockIdx.x * 64;
    const int l0 = blockIdx.y * 64;
    const int b  = blockIdx.z;
    const float* xb = x + (size_t)b * LL * DD;
    u16* x16b = x16 + (size_t)b * LL * DD;
    u16* xtb  = xt  + (size_t)b * DD * LL;
    #pragma unroll
    for (int p = 0; p < 4; ++p) {
        int idx = p * 256 + threadIdx.x;
        int r = idx >> 4, c4 = (idx & 15) * 4;       // r: l-offset, c4: d-offset
        float4 v = *(const float4*)(xb + (size_t)(l0 + r) * DD + d0 + c4);
        ushort4 h;
        h.x = f2bf(v.x); h.y = f2bf(v.y); h.z = f2bf(v.z); h.w = f2bf(v.w);
        *(ushort4*)(x16b + (size_t)(l0 + r) * DD + d0 + c4) = h;
        tile[r * 65 + c4]     = h.x;
        tile[r * 65 + c4 + 1] = h.y;
        tile[r * 65 + c4 + 2] = h.z;
        tile[r * 65 + c4 + 3] = h.w;
    }
    __syncthreads();
    #pragma unroll
    for (int p = 0; p < 4; ++p) {
        int idx = p * 256 + threadIdx.x;
        int r = idx >> 4, c4 = (idx & 15) * 4;       // r: d-offset, c4: l-offset
        ushort4 h;
        h.x = tile[(c4    ) * 65 + r];
        h.y = tile[(c4 + 1) * 65 + r];
        h.z = tile[(c4 + 2) * 65 + r];
        h.w = tile[(c4 + 3) * 65 + r];
        *(ushort4*)(xtb + (size_t)(d0 + r) * LL + l0 + c4) = h;
    }
}

// ---------------- GEMM1: att^T-tile = x_tile . U^T  (m=l staged, n=y from L2) ----------------
// A (x16 tile, 128 l-rows) staged via global_load_lds into dbuf LDS (1 barrier/iter);
// B (U16) fragment-loaded straight from L2 (3 MB, resident). Epilogue: ushort4 stores along l.
__global__ __launch_bounds__(256) void gemm1_k(const u16* __restrict__ Xg, const u16* __restrict__ Ug,
                                               u16* __restrict__ Cg) {
    __shared__ u16 As[8192];          // 2 x (128 rows x 32 k) bf16 = 16 KB
    const int id = blockIdx.x;
    const int b = id & 7;
    const int r = id >> 3;
    const int nblk = r & 15;          // y-block, inner: 16 y-blocks share one staged x-tile
    const int mblk = r >> 4;          // l-block
    const u16* A = Xg + (size_t)b * LL * DD;
    u16* C = Cg + (size_t)b * (size_t)YY * LL;
    const int m0 = mblk * 128;        // l
    const int n0 = nblk * 128;        // y
    const int t = threadIdx.x;
    const int lane = t & 63;
    const int wave = t >> 6;
    const int wm = (wave >> 1) * 64;  // l-offset of wave
    const int wn = (wave & 1) * 64;   // y-offset of wave
    const int ln = lane & 15;
    const int qd = lane >> 4;
    const int swz = (qd ^ ((ln >> 1) & 3)) * 8;

    // A staging: 512 chunks of 16B; thread covers chunks t and t+256 (rows t>>2, t>>2+64)
    const int kq0 = (t & 3) ^ ((t >> 3) & 3);
    const u16* Ab0 = A + (size_t)(m0 + (t >> 2)) * DD + kq0 * 8;
    const u16* Ab1 = A + (size_t)(m0 + (t >> 2) + 64) * DD + kq0 * 8;
    const int c0 = t, c1 = t + 256;

    // B fragment base pointers (global, L2-hot)
    const u16* Bp[4];
    #pragma unroll
    for (int j = 0; j < 4; ++j)
        Bp[j] = Ug + (size_t)(n0 + wn + j * 16 + ln) * DD + qd * 8;

    // prologue: stage tile 0 into buf 0
    __builtin_amdgcn_global_load_lds((const __attribute__((address_space(1))) unsigned int*)(Ab0),
                                     (__attribute__((address_space(3))) unsigned int*)(As + c0 * 8), 16, 0, 0);
    __builtin_amdgcn_global_load_lds((const __attribute__((address_space(1))) unsigned int*)(Ab1),
                                     (__attribute__((address_space(3))) unsigned int*)(As + c1 * 8), 16, 0, 0);

    f32x4 acc[4][4] = {};
    int cur = 0;
    const int KT = DD / 32;           // 24
    for (int kt = 0; kt < KT; ++kt) {
        __syncthreads();              // drains A loads for buf[cur]; protects buf[cur^1] frag reads
        // B frags FIRST (so their waitcnt doesn't drain the A prefetch behind them)
        bf16x8 bfr[4];
        #pragma unroll
        for (int j = 0; j < 4; ++j)
            bfr[j] = *(const bf16x8*)(Bp[j] + kt * 32);
        // A prefetch for next tile into the other buffer
        if (kt + 1 < KT) {
            const int k0 = (kt + 1) * 32;
            const int nb = (cur ^ 1) * 4096;
            __builtin_amdgcn_global_load_lds((const __attribute__((address_space(1))) unsigned int*)(Ab0 + k0),
                                             (__attribute__((address_space(3))) unsigned int*)(As + nb + c0 * 8), 16, 0, 0);
            __builtin_amdgcn_global_load_lds((const __attribute__((address_space(1))) unsigned int*)(Ab1 + k0),
                                             (__attribute__((address_space(3))) unsigned int*)(As + nb + c1 * 8), 16, 0, 0);
        }
        const u16* Ab = As + cur * 4096;
        bf16x8 af[4];
        #pragma unroll
        for (int i = 0; i < 4; ++i)
            af[i] = *(const bf16x8*)(Ab + (wm + i * 16 + ln) * 32 + swz);
        #pragma unroll
        for (int i = 0; i < 4; ++i)
            #pragma unroll
            for (int j = 0; j < 4; ++j)
                acc[i][j] = __builtin_amdgcn_mfma_f32_16x16x32_bf16(af[i], bfr[j], acc[i][j], 0, 0, 0);
        cur ^= 1;
    }
    // epilogue: acc[i][j][rr] = att[y = n0+wn+j*16+ln][l = m0+wm+i*16+qd*4+rr] -> ushort4 along l
    #pragma unroll
    for (int j = 0; j < 4; ++j) {
        const size_t yrow = (size_t)(n0 + wn + j * 16 + ln) * LL;
        #pragma unroll
        for (int i = 0; i < 4; ++i) {
            ushort4 h;
            h.x = f2bf(acc[i][j][0]); h.y = f2bf(acc[i][j][1]);
            h.z = f2bf(acc[i][j][2]); h.w = f2bf(acc[i][j][3]);
            *(ushort4*)(C + yrow + m0 + wm + i * 16 + qd * 4) = h;
        }
    }
}

// ---------------- GEMM2: m_tile = alpha . xt^T, split-K=2, fused fw-dot -> y atomics --------
// A (att tile) staged via dbuf LDS; B (xt) fragment-loaded from L2/L3.
__global__ __launch_bounds__(256) void gemm2_k(const u16* __restrict__ Ag, const u16* __restrict__ Bg,
                                               const float* __restrict__ fw, float* __restrict__ yout) {
    __shared__ u16 As[8192];
    const int id = blockIdx.x;
    const int b = id & 7;
    const int r2 = id >> 3;              // 0..191
    const int half = r2 / 96;
    const int rr_ = r2 % 96;
    const int nblk = rr_ % 6;            // d-block, inner: 6 share one att y-tile
    const int yblk = rr_ / 6;
    const int ktOff = half * 64;
    const u16* A = Ag + (size_t)b * (size_t)YY * LL;
    const u16* Bx = Bg + (size_t)b * (size_t)DD * LL;
    const int m0 = yblk * 128;           // y
    const int n0 = nblk * 128;           // d
    const int t = threadIdx.x;
    const int lane = t & 63;
    const int wave = t >> 6;
    const int wm = (wave >> 1) * 64;
    const int wn = (wave & 1) * 64;
    const int ln = lane & 15;
    const int qd = lane >> 4;
    const int swz = (qd ^ ((ln >> 1) & 3)) * 8;

    const int kq0 = (t & 3) ^ ((t >> 3) & 3);
    const u16* Ab0 = A + (size_t)(m0 + (t >> 2)) * LL + kq0 * 8;
    const u16* Ab1 = A + (size_t)(m0 + (t >> 2) + 64) * LL + kq0 * 8;
    const int c0 = t, c1 = t + 256;

    const u16* Bp[4];
    #pragma unroll
    for (int j = 0; j < 4; ++j)
        Bp[j] = Bx + (size_t)(n0 + wn + j * 16 + ln) * LL + qd * 8;

    {
        const int k0 = ktOff * 32;
        __builtin_amdgcn_global_load_lds((const __attribute__((address_space(1))) unsigned int*)(Ab0 + k0),
                                         (__attribute__((address_space(3))) unsigned int*)(As + c0 * 8), 16, 0, 0);
        __builtin_amdgcn_global_load_lds((const __attribute__((address_space(1))) unsigned int*)(Ab1 + k0),
                                         (__attribute__((address_space(3))) unsigned int*)(As + c1 * 8), 16, 0, 0);
    }

    f32x4 acc[4][4] = {};
    int cur = 0;
    for (int kt = ktOff; kt < ktOff + 64; ++kt) {
        __syncthreads();
        bf16x8 bfr[4];
        #pragma unroll
        for (int j = 0; j < 4; ++j)
            bfr[j] = *(const bf16x8*)(Bp[j] + kt * 32);
        if (kt + 1 < ktOff + 64) {
            const int k0 = (kt + 1) * 32;
            const int nb = (cur ^ 1) * 4096;
            __builtin_amdgcn_global_load_lds((const __attribute__((address_space(1))) unsigned int*)(Ab0 + k0),
                                             (__attribute__((address_space(3))) unsigned int*)(As + nb + c0 * 8), 16, 0, 0);
            __builtin_amdgcn_global_load_lds((const __attribute__((address_space(1))) unsigned int*)(Ab1 + k0),
                                             (__attribute__((address_space(3))) unsigned int*)(As + nb + c1 * 8), 16, 0, 0);
        }
        const u16* Ab = As + cur * 4096;
        bf16x8 af[4];
        #pragma unroll
        for (int i = 0; i < 4; ++i)
            af[i] = *(const bf16x8*)(Ab + (wm + i * 16 + ln) * 32 + swz);
        #pragma unroll
        for (int i = 0; i < 4; ++i)
            #pragma unroll
            for (int j = 0; j < 4; ++j)
                acc[i][j] = __builtin_amdgcn_mfma_f32_16x16x32_bf16(af[i], bfr[j], acc[i][j], 0, 0, 0);
        cur ^= 1;
    }
    // Fused epilogue: per-row partial dot with fw over this block's 128 d-cols.
    #pragma unroll
    for (int i = 0; i < 4; ++i) {
        #pragma unroll
        for (int rr = 0; rr < 4; ++rr) {
            const int row = m0 + wm + i * 16 + qd * 4 + rr;
            const float* fwr = fw + (size_t)row * DD + n0 + wn;
            float s = acc[i][0][rr] * fwr[ln]
                    + acc[i][1][rr] * fwr[16 + ln]
                    + acc[i][2][rr] * fwr[32 + ln]
                    + acc[i][3][rr] * fwr[48 + ln];
            #pragma unroll
            for (int off = 1; off < 16; off <<= 1) s += __shfl_xor(s, off, 64);
            if (ln == 0) atomicAdd(&yout[(size_t)b * YY + row], s);
        }
    }
}

// ---------------- row softmax over L=4096, in-place bf16, one block per (b,y) row --------
__global__ __launch_bounds__(256) void softmax_rows_k(u16* __restrict__ att) {
    __shared__ float red[4];
    const int t = threadIdx.x;
    uint4* row = (uint4*)(att + (size_t)blockIdx.x * LL);   // 512 uint4/row, 2 per thread
    uint4 pa = row[t * 2], pb = row[t * 2 + 1];
    float v[16];
    {
        uint32_t w[8] = {pa.x, pa.y, pa.z, pa.w, pb.x, pb.y, pb.z, pb.w};
        #pragma unroll
        for (int i = 0; i < 8; ++i) {
            v[2 * i]     = __uint_as_float((w[i] & 0xffffu) << 16);
            v[2 * i + 1] = __uint_as_float(w[i] & 0xffff0000u);
        }
    }
    float mx = v[0];
    #pragma unroll
    for (int i = 1; i < 16; ++i) mx = fmaxf(mx, v[i]);
    for (int o = 32; o; o >>= 1) mx = fmaxf(mx, __shfl_down(mx, o, 64));
    if ((t & 63) == 0) red[t >> 6] = mx;
    __syncthreads();
    if (t == 0) red[0] = fmaxf(fmaxf(red[0], red[1]), fmaxf(red[2], red[3]));
    __syncthreads();
    mx = red[0];
    float e[16], s = 0.f;
    #pragma unroll
    for (int i = 0; i < 16; ++i) { e[i] = __expf(v[i] - mx); s += e[i]; }
    for (int o = 32; o; o >>= 1) s += __shfl_down(s, o, 64);
    __syncthreads();
    if ((t & 63) == 0) red[t >> 6] = s;
    __syncthreads();
    if (t == 0) red[0] = red[0] + red[1] + red[2] + red[3];
    __syncthreads();
    const float inv = 1.0f / red[0];
    uint32_t w[8];
    #pragma unroll
    for (int i = 0; i < 8; ++i) {
        u16 lo = f2bf(e[2 * i] * inv), hi = f2bf(e[2 * i + 1] * inv);
        w[i] = (uint32_t)lo | ((uint32_t)hi << 16);
    }
    row[t * 2]     = make_uint4(w[0], w[1], w[2], w[3]);
    row[t * 2 + 1] = make_uint4(w[4], w[5], w[6], w[7]);
}

// -------- finalize: y += bias (writeback), CE loss = mean_b( lse(y[b]) - y[b][tgt[b]] ) --------
__global__ __launch_bounds__(256) void ce_loss_k(float* __restrict__ yv,
                                                 const float* __restrict__ fb,
                                                 const int* __restrict__ tgt,
                                                 float* __restrict__ out0) {
    __shared__ float part[8];
    const int t = threadIdx.x;
    const int wave = t >> 6, lane = t & 63;
    #pragma unroll
    for (int rep = 0; rep < 2; ++rep) {
        const int b = wave + rep * 4;
        float* row = yv + b * YY;
        const int tg = tgt[b];
        float v[32];
        float mx = -3.0e38f;
        #pragma unroll
        for (int i = 0; i < 32; ++i) {
            v[i] = row[lane + 64 * i] + fb[lane + 64 * i];
            mx = fmaxf(mx, v[i]);
        }
        float tv = 0.f;
        #pragma unroll
        for (int i = 0; i < 32; ++i) {
            if (lane + 64 * i == tg) tv = v[i];
            row[lane + 64 * i] = v[i];          // write back biased y
        }
        for (int o = 32; o; o >>= 1) mx = fmaxf(mx, __shfl_down(mx, o, 64));
        mx = __shfl(mx, 0, 64);
        float s = 0.f;
        #pragma unroll
        for (int i = 0; i < 32; ++i) s += __expf(v[i] - mx);
        for (int o = 32; o; o >>= 1) { s += __shfl_down(s, o, 64); tv += __shfl_down(tv, o, 64); }
        if (lane == 0) part[b] = mx + logf(s) - tv;
    }
    __syncthreads();
    if (t == 0) {
        float tot = 0.f;
        #pragma unroll
        for (int i = 0; i < 8; ++i) tot += part[i];
        out0[0] = tot * 0.125f;
    }
}

extern "C" void kernel_launch(void* const* d_in, const int* in_sizes, int n_in,
                              void* d_out, int out_size, void* d_ws, size_t ws_size,
                              hipStream_t stream) {
    const float* x   = (const float*)d_in[0];   // (B,L,D)
    const float* Uw  = (const float*)d_in[1];   // (Y,D)
    const float* fw  = (const float*)d_in[2];   // (Y,D)
    const float* fb  = (const float*)d_in[3];   // (Y,)
    const int*   tgt = (const int*)d_in[4];     // (B,)
    float* out = (float*)d_out;                 // [loss, y(B*Y)]

    char* ws = (char*)d_ws;
    u16*  x16  = (u16*)(ws);                          // B*L*D bf16   = 50,331,648 B
    u16*  xt   = (u16*)(ws + 50331648);               // B*D*L bf16   = 50,331,648 B
    u16*  U16  = (u16*)(ws + 100663296);              // Y*D bf16     =  3,145,728 B
    u16*  att  = (u16*)(ws + 103809024);              // B*Y*L bf16   = 134,217,728 B  (tot 238 MB)

    hipMemsetAsync(out + 1, 0, (size_t)BB * YY * sizeof(float), stream);  // y accumulator = 0
    cast_u_k<<<1536, 256, 0, stream>>>(Uw, U16);
    cast_transpose_x_k<<<dim3(DD / 64, LL / 64, BB), 256, 0, stream>>>(x, x16, xt);

    // GEMM1: att[b][y][l], m-dim=l (x16 staged), n-dim=y (U16 from L2). 32*16*8 = 4096 blocks.
    gemm1_k<<<(LL / 128) * (YY / 128) * BB, 256, 0, stream>>>(x16, U16, att);

    softmax_rows_k<<<BB * YY, 256, 0, stream>>>(att);

    // GEMM2: split-K=2, A=att staged dbuf, B=xt from L2, fused fw-dot -> y atomics.
    gemm2_k<<<(DD / 128) * (YY / 128) * BB * 2, 256, 0, stream>>>(att, xt, fw, out + 1);

    ce_loss_k<<<1, 256, 0, stream>>>(out + 1, fb, tgt, out);
}

// Round 5
// 478.408 us; speedup vs baseline: 1.4267x; 1.4267x over previous
//
#include <hip/hip_runtime.h>
#include <hip/hip_bf16.h>
#include <cstdint>

// Problem constants: B=8, L=4096, D=768, Y=2048
#define BB 8
#define LL 4096
#define DD 768
#define YY 2048

typedef unsigned short u16;
typedef __bf16 bf16x8 __attribute__((ext_vector_type(8)));
typedef float f32x4 __attribute__((ext_vector_type(4)));

__device__ __forceinline__ u16 f2bf(float f) {
    uint32_t u = __float_as_uint(f);
    u += 0x7fffu + ((u >> 16) & 1u);   // RNE
    return (u16)(u >> 16);
}

// ---------------- cast U (Y*D = 1,572,864 floats) ----------------
__global__ __launch_bounds__(256) void cast_u_k(const float* __restrict__ U, u16* __restrict__ U16) {
    int i = blockIdx.x * 256 + threadIdx.x;          // one float4 per thread
    float4 v = ((const float4*)U)[i];
    ushort4 h;
    h.x = f2bf(v.x); h.y = f2bf(v.y); h.z = f2bf(v.z); h.w = f2bf(v.w);
    ((ushort4*)U16)[i] = h;
}

// -------- cast x -> x16 (B,L,D) bf16 AND xt (B,D,L) bf16 (transpose) --------
__global__ __launch_bounds__(256) void cast_transpose_x_k(const float* __restrict__ x,
                                                          u16* __restrict__ x16,
                                                          u16* __restrict__ xt) {
    __shared__ u16 tile[64 * 65];
    const int d0 = blockIdx.x * 64;
    const int l0 = blockIdx.y * 64;
    const int b  = blockIdx.z;
    const float* xb = x + (size_t)b * LL * DD;
    u16* x16b = x16 + (size_t)b * LL * DD;
    u16* xtb  = xt  + (size_t)b * DD * LL;
    #pragma unroll
    for (int p = 0; p < 4; ++p) {
        int idx = p * 256 + threadIdx.x;
        int r = idx >> 4, c4 = (idx & 15) * 4;       // r: l-offset, c4: d-offset
        float4 v = *(const float4*)(xb + (size_t)(l0 + r) * DD + d0 + c4);
        ushort4 h;
        h.x = f2bf(v.x); h.y = f2bf(v.y); h.z = f2bf(v.z); h.w = f2bf(v.w);
        *(ushort4*)(x16b + (size_t)(l0 + r) * DD + d0 + c4) = h;
        tile[r * 65 + c4]     = h.x;
        tile[r * 65 + c4 + 1] = h.y;
        tile[r * 65 + c4 + 2] = h.z;
        tile[r * 65 + c4 + 3] = h.w;
    }
    __syncthreads();
    #pragma unroll
    for (int p = 0; p < 4; ++p) {
        int idx = p * 256 + threadIdx.x;
        int r = idx >> 4, c4 = (idx & 15) * 4;       // r: d-offset, c4: l-offset
        ushort4 h;
        h.x = tile[(c4    ) * 65 + r];
        h.y = tile[(c4 + 1) * 65 + r];
        h.z = tile[(c4 + 2) * 65 + r];
        h.w = tile[(c4 + 3) * 65 + r];
        *(ushort4*)(xtb + (size_t)(d0 + r) * LL + l0 + c4) = h;
    }
}

// ---------------- GEMM1: expatt = exp(U . x^T), bf16 out + rowsum atomics (NT, K=768) ------
// Round-3 structure (both operands staged via global_load_lds, 2-barrier K-loop,
// swizzled conflict-free LDS). Epilogue applies exp() to the fp32 acc, writes exp(att)
// bf16, and atomically accumulates per-y-row sums (fp32) -> softmax fused away.
// NOTE (R4 lesson): do NOT stream fragments per-lane from L2 — uncoalesced 16-line
// scatters + exposed latency regressed 156->260 us.
__global__ __launch_bounds__(256) void gemm1_k(const u16* __restrict__ A, const u16* __restrict__ B,
                                               u16* __restrict__ C, float* __restrict__ rowsum) {
    __shared__ u16 As[128 * 32];
    __shared__ u16 Bs[128 * 32];
    const int id = blockIdx.x;
    const int b = id & 7;
    const int r = id >> 3;
    const int ny = YY / 128;
    const int yblk = r % ny;      // y-inner: blocks sharing an x16 tile adjacent on XCD
    const int nblk = r / ny;
    B += (size_t)b * LL * DD;
    C += (size_t)b * (size_t)YY * LL;
    rowsum += (size_t)b * YY;
    const int m0 = yblk * 128;    // y
    const int n0 = nblk * 128;    // l
    const int t = threadIdx.x;
    const int lane = t & 63;
    const int wave = t >> 6;
    const int wm = (wave >> 1) * 64;
    const int wn = (wave & 1) * 64;
    const int ln = lane & 15;
    const int qd = lane >> 4;
    const int swz = (qd ^ ((ln >> 1) & 3)) * 8;

    const int row0 = t >> 2;
    const int kq0  = (t & 3) ^ ((t >> 3) & 3);
    const u16* Ab0 = A + (size_t)(m0 + row0) * DD + kq0 * 8;
    const u16* Ab1 = A + (size_t)(m0 + row0 + 64) * DD + kq0 * 8;
    const u16* Bb0 = B + (size_t)(n0 + row0) * DD + kq0 * 8;
    const u16* Bb1 = B + (size_t)(n0 + row0 + 64) * DD + kq0 * 8;
    const int c0 = t, c1 = t + 256;

    f32x4 acc[4][4] = {};
    for (int kt = 0; kt < DD / 32; ++kt) {
        const int k0 = kt << 5;
        __syncthreads();
        __builtin_amdgcn_global_load_lds((const __attribute__((address_space(1))) unsigned int*)(Ab0 + k0),
                                         (__attribute__((address_space(3))) unsigned int*)(As + c0 * 8), 16, 0, 0);
        __builtin_amdgcn_global_load_lds((const __attribute__((address_space(1))) unsigned int*)(Ab1 + k0),
                                         (__attribute__((address_space(3))) unsigned int*)(As + c1 * 8), 16, 0, 0);
        __builtin_amdgcn_global_load_lds((const __attribute__((address_space(1))) unsigned int*)(Bb0 + k0),
                                         (__attribute__((address_space(3))) unsigned int*)(Bs + c0 * 8), 16, 0, 0);
        __builtin_amdgcn_global_load_lds((const __attribute__((address_space(1))) unsigned int*)(Bb1 + k0),
                                         (__attribute__((address_space(3))) unsigned int*)(Bs + c1 * 8), 16, 0, 0);
        __syncthreads();
        bf16x8 af[4], bfr[4];
        #pragma unroll
        for (int i = 0; i < 4; ++i) {
            af[i]  = *(const bf16x8*)(As + (wm + i * 16 + ln) * 32 + swz);
            bfr[i] = *(const bf16x8*)(Bs + (wn + i * 16 + ln) * 32 + swz);
        }
        #pragma unroll
        for (int i = 0; i < 4; ++i)
            #pragma unroll
            for (int j = 0; j < 4; ++j)
                acc[i][j] = __builtin_amdgcn_mfma_f32_16x16x32_bf16(af[i], bfr[j], acc[i][j], 0, 0, 0);
    }
    // epilogue: row(y)=m0+wm+i*16+qd*4+rr, col(l)=n0+wn+j*16+ln
    // exp + store bf16; per-row sum over this block's 64 l-cols -> atomicAdd
    #pragma unroll
    for (int i = 0; i < 4; ++i) {
        #pragma unroll
        for (int rr = 0; rr < 4; ++rr) {
            const int row = m0 + wm + i * 16 + qd * 4 + rr;
            float rs = 0.f;
            #pragma unroll
            for (int j = 0; j < 4; ++j) {
                float e = __expf(acc[i][j][rr]);
                rs += e;
                C[(size_t)row * LL + n0 + wn + j * 16 + ln] = f2bf(e);
            }
            #pragma unroll
            for (int off = 1; off < 16; off <<= 1) rs += __shfl_xor(rs, off, 64);
            if (ln == 0) atomicAdd(&rowsum[row], rs);
        }
    }
}

// ---------------- GEMM2 (split-K=2, fused fw-dot + 1/rowsum epilogue) ----------------
// m_tile = expatt(Y x L-half) . xt(D x L-half)^T ; y[b][row] += (fw-dot) / rowsum[row]
__global__ __launch_bounds__(256) void gemm2_k(const u16* __restrict__ A, const u16* __restrict__ B,
                                               const float* __restrict__ fw,
                                               const float* __restrict__ rowsum,
                                               float* __restrict__ yout) {
    __shared__ u16 As[128 * 32];
    __shared__ u16 Bs[128 * 32];
    const int id = blockIdx.x;
    const int b = id & 7;
    const int r2 = id >> 3;              // 0..191
    const int half = r2 / 96;
    const int rr_ = r2 % 96;
    const int nblk = rr_ % 6;            // n-inner: blocks sharing an att tile adjacent on XCD
    const int yblk = rr_ / 6;
    const int ktOff = half * 64;
    A += (size_t)b * (size_t)YY * LL;
    B += (size_t)b * (size_t)DD * LL;
    rowsum += (size_t)b * YY;
    const int m0 = yblk * 128;
    const int n0 = nblk * 128;
    const int t = threadIdx.x;
    const int lane = t & 63;
    const int wave = t >> 6;
    const int wm = (wave >> 1) * 64;
    const int wn = (wave & 1) * 64;
    const int ln = lane & 15;
    const int qd = lane >> 4;
    const int swz = (qd ^ ((ln >> 1) & 3)) * 8;

    const int row0 = t >> 2;
    const int kq0  = (t & 3) ^ ((t >> 3) & 3);
    const u16* Ab0 = A + (size_t)(m0 + row0) * LL + kq0 * 8;
    const u16* Ab1 = A + (size_t)(m0 + row0 + 64) * LL + kq0 * 8;
    const u16* Bb0 = B + (size_t)(n0 + row0) * LL + kq0 * 8;
    const u16* Bb1 = B + (size_t)(n0 + row0 + 64) * LL + kq0 * 8;
    const int c0 = t, c1 = t + 256;

    f32x4 acc[4][4] = {};
    for (int kt = ktOff; kt < ktOff + 64; ++kt) {
        const int k0 = kt << 5;
        __syncthreads();
        __builtin_amdgcn_global_load_lds((const __attribute__((address_space(1))) unsigned int*)(Ab0 + k0),
                                         (__attribute__((address_space(3))) unsigned int*)(As + c0 * 8), 16, 0, 0);
        __builtin_amdgcn_global_load_lds((const __attribute__((address_space(1))) unsigned int*)(Ab1 + k0),
                                         (__attribute__((address_space(3))) unsigned int*)(As + c1 * 8), 16, 0, 0);
        __builtin_amdgcn_global_load_lds((const __attribute__((address_space(1))) unsigned int*)(Bb0 + k0),
                                         (__attribute__((address_space(3))) unsigned int*)(Bs + c0 * 8), 16, 0, 0);
        __builtin_amdgcn_global_load_lds((const __attribute__((address_space(1))) unsigned int*)(Bb1 + k0),
                                         (__attribute__((address_space(3))) unsigned int*)(Bs + c1 * 8), 16, 0, 0);
        __syncthreads();
        bf16x8 af[4], bfr[4];
        #pragma unroll
        for (int i = 0; i < 4; ++i) {
            af[i]  = *(const bf16x8*)(As + (wm + i * 16 + ln) * 32 + swz);
            bfr[i] = *(const bf16x8*)(Bs + (wn + i * 16 + ln) * 32 + swz);
        }
        #pragma unroll
        for (int i = 0; i < 4; ++i)
            #pragma unroll
            for (int j = 0; j < 4; ++j)
                acc[i][j] = __builtin_amdgcn_mfma_f32_16x16x32_bf16(af[i], bfr[j], acc[i][j], 0, 0, 0);
    }
    // Fused epilogue: per-row partial dot with fw over this block's 128 d-cols, / rowsum.
    #pragma unroll
    for (int i = 0; i < 4; ++i) {
        #pragma unroll
        for (int rr = 0; rr < 4; ++rr) {
            const int row = m0 + wm + i * 16 + qd * 4 + rr;
            const float* fwr = fw + (size_t)row * DD + n0 + wn;
            float s = acc[i][0][rr] * fwr[ln]
                    + acc[i][1][rr] * fwr[16 + ln]
                    + acc[i][2][rr] * fwr[32 + ln]
                    + acc[i][3][rr] * fwr[48 + ln];
            #pragma unroll
            for (int off = 1; off < 16; off <<= 1) s += __shfl_xor(s, off, 64);
            if (ln == 0) atomicAdd(&yout[(size_t)b * YY + row], s * (1.0f / rowsum[row]));
        }
    }
}

// -------- finalize: y += bias (writeback), CE loss = mean_b( lse(y[b]) - y[b][tgt[b]] ) --------
__global__ __launch_bounds__(256) void ce_loss_k(float* __restrict__ yv,
                                                 const float* __restrict__ fb,
                                                 const int* __restrict__ tgt,
                                                 float* __restrict__ out0) {
    __shared__ float part[8];
    const int t = threadIdx.x;
    const int wave = t >> 6, lane = t & 63;
    #pragma unroll
    for (int rep = 0; rep < 2; ++rep) {
        const int b = wave + rep * 4;
        float* row = yv + b * YY;
        const int tg = tgt[b];
        float v[32];
        float mx = -3.0e38f;
        #pragma unroll
        for (int i = 0; i < 32; ++i) {
            v[i] = row[lane + 64 * i] + fb[lane + 64 * i];
            mx = fmaxf(mx, v[i]);
        }
        float tv = 0.f;
        #pragma unroll
        for (int i = 0; i < 32; ++i) {
            if (lane + 64 * i == tg) tv = v[i];
            row[lane + 64 * i] = v[i];          // write back biased y
        }
        for (int o = 32; o; o >>= 1) mx = fmaxf(mx, __shfl_down(mx, o, 64));
        mx = __shfl(mx, 0, 64);
        float s = 0.f;
        #pragma unroll
        for (int i = 0; i < 32; ++i) s += __expf(v[i] - mx);
        for (int o = 32; o; o >>= 1) { s += __shfl_down(s, o, 64); tv += __shfl_down(tv, o, 64); }
        if (lane == 0) part[b] = mx + logf(s) - tv;
    }
    __syncthreads();
    if (t == 0) {
        float tot = 0.f;
        #pragma unroll
        for (int i = 0; i < 8; ++i) tot += part[i];
        out0[0] = tot * 0.125f;
    }
}

extern "C" void kernel_launch(void* const* d_in, const int* in_sizes, int n_in,
                              void* d_out, int out_size, void* d_ws, size_t ws_size,
                              hipStream_t stream) {
    const float* x   = (const float*)d_in[0];   // (B,L,D)
    const float* Uw  = (const float*)d_in[1];   // (Y,D)
    const float* fw  = (const float*)d_in[2];   // (Y,D)
    const float* fb  = (const float*)d_in[3];   // (Y,)
    const int*   tgt = (const int*)d_in[4];     // (B,)
    float* out = (float*)d_out;                 // [loss, y(B*Y)]

    char* ws = (char*)d_ws;
    u16*  x16  = (u16*)(ws);                          // B*L*D bf16   = 50,331,648 B
    u16*  xt   = (u16*)(ws + 50331648);               // B*D*L bf16   = 50,331,648 B
    u16*  U16  = (u16*)(ws + 100663296);              // Y*D bf16     =  3,145,728 B
    u16*  att  = (u16*)(ws + 103809024);              // B*Y*L bf16   = 134,217,728 B
    float* rowsum = (float*)(ws + 238026752);         // B*Y fp32     = 65,536 B

    hipMemsetAsync(out + 1, 0, (size_t)BB * YY * sizeof(float), stream);  // y accumulator
    hipMemsetAsync(rowsum, 0, (size_t)BB * YY * sizeof(float), stream);   // softmax denom
    cast_u_k<<<1536, 256, 0, stream>>>(Uw, U16);
    cast_transpose_x_k<<<dim3(DD / 64, LL / 64, BB), 256, 0, stream>>>(x, x16, xt);

    // GEMM1: expatt[b](Y x L) = exp(U16 . x16[b]^T), + rowsum atomics  [NT, K=768]
    gemm1_k<<<(LL / 128) * (YY / 128) * BB, 256, 0, stream>>>(U16, x16, att, rowsum);

    // GEMM2: split-K=2, fused fw-dot + 1/rowsum -> y atomics (no softmax kernel, no m buffer)
    gemm2_k<<<(DD / 128) * (YY / 128) * BB * 2, 256, 0, stream>>>(att, xt, fw, rowsum, out + 1);

    ce_loss_k<<<1, 256, 0, stream>>>(out + 1, fb, tgt, out);
}